// Round 3
// baseline (258.989 us; speedup 1.0000x reference)
//
#include <hip/hip_runtime.h>

// FeatLUT: out[f] = quantize( mean_p( msb[idx_m(p)][f] + lsb[idx_l(p)][f] ) )
// idx = 16*(289*c0 + 17*c1 + c2)  -> only 17^3 = 4913 distinct rows used.
// R1 lesson: same-cacheline global atomics serialize (417us) -> per-block partials.
// R2 lesson: per-block fixed cost (hist clear + 4913-bin dot) dominates at 1024
// blocks -> fewer, fatter blocks (512 x 1024thr), branchless tail, fused finalize.

#define NBINS 4913            // 17^3
#define NPIX  (2048 * 2048)   // 4194304
#define G4    (NPIX / 4)      // 1048576 float4 groups per channel plane
#define NFEAT 20
#define MB    512             // main grid: 2 blocks/CU resident
#define MT    1024            // threads/block (16 waves)

// ---------------------------------------------------------------------------
// Kernel 0: compact used LUT rows (row 16*j) into dense 20-byte rows (5 dwords)
// and zero the completion counter. Handles both harness table layouts:
// (a) raw int8 bytes, (b) int8 widened to int32. Random packed bytes
// essentially never look like 16 consecutive ints in [-32,32).
// ---------------------------------------------------------------------------
__global__ __launch_bounds__(256) void compact_k(const int* __restrict__ msb,
                                                 const int* __restrict__ lsb,
                                                 int* __restrict__ cm,
                                                 int* __restrict__ cl,
                                                 unsigned* __restrict__ done) {
    if (blockIdx.x == 0 && threadIdx.x == 0) *done = 0u;

    int ok = 1;
#pragma unroll
    for (int i = 0; i < 16; ++i) {
        int v = msb[i];
        ok &= (v >= -32 && v < 32);
    }
    const bool is_int32 = (ok != 0);

    const int total = NBINS * 5;  // dwords per compact table
    int t = blockIdx.x * 256 + threadIdx.x;
    const int stride = gridDim.x * 256;
    for (; t < total; t += stride) {
        int j = t / 5;
        int k = t - j * 5;
        int wm, wl;
        if (is_int32) {
            // int per element; row 16j starts at element 16j*20 = 320j
            const int* rm = msb + j * 320 + k * 4;
            const int* rl = lsb + j * 320 + k * 4;
            wm = (int)((unsigned)(rm[0] & 0xff) | ((unsigned)(rm[1] & 0xff) << 8) |
                       ((unsigned)(rm[2] & 0xff) << 16) | ((unsigned)(rm[3] & 0xff) << 24));
            wl = (int)((unsigned)(rl[0] & 0xff) | ((unsigned)(rl[1] & 0xff) << 8) |
                       ((unsigned)(rl[2] & 0xff) << 16) | ((unsigned)(rl[3] & 0xff) << 24));
        } else {
            // raw int8; row 16j at byte 320j -> dword 80j
            wm = msb[j * 80 + k];
            wl = lsb[j * 80 + k];
        }
        cm[t] = wm;
        cl[t] = wl;
    }
}

// ---------------------------------------------------------------------------
// Kernel 1: main. MB x MT.
//  - LDS histograms (2 x 4913 ints), float4 streaming (2 exact iters)
//  - branchless per-block dot vs compact tables, wave reduce, per-block partial
//  - last-arriving block reduces the 512 partials and writes d_out (saves a launch)
// ---------------------------------------------------------------------------
__global__ __launch_bounds__(MT) void feat_main(const float* __restrict__ xin,
                                                const float* __restrict__ xs,
                                                const int* __restrict__ cm,
                                                const int* __restrict__ cl,
                                                int* __restrict__ partial,
                                                unsigned* __restrict__ done,
                                                float* __restrict__ out) {
    __shared__ int hist[2 * NBINS];  // [0,NBINS): msb, [NBINS,2*NBINS): lsb
    __shared__ int wsum[MT / 64][NFEAT];
    __shared__ unsigned is_last;
    for (int i = threadIdx.x; i < 2 * NBINS; i += MT) hist[i] = 0;
    __syncthreads();

    const float4* a = (const float4*)xin;
    const float4* b = (const float4*)xs;
    for (int g = blockIdx.x * MT + threadIdx.x; g < G4; g += MB * MT) {
        float4 a0 = a[g], a1 = a[g + G4], a2 = a[g + 2 * G4];
        float4 b0 = b[g], b1 = b[g + G4], b2 = b[g + 2 * G4];

        int m0 = (int)fmaf(a0.x, 289.0f, fmaf(a1.x, 17.0f, a2.x));
        int m1 = (int)fmaf(a0.y, 289.0f, fmaf(a1.y, 17.0f, a2.y));
        int m2 = (int)fmaf(a0.z, 289.0f, fmaf(a1.z, 17.0f, a2.z));
        int m3 = (int)fmaf(a0.w, 289.0f, fmaf(a1.w, 17.0f, a2.w));
        int s0 = (int)fmaf(b0.x, 289.0f, fmaf(b1.x, 17.0f, b2.x));
        int s1 = (int)fmaf(b0.y, 289.0f, fmaf(b1.y, 17.0f, b2.y));
        int s2 = (int)fmaf(b0.z, 289.0f, fmaf(b1.z, 17.0f, b2.z));
        int s3 = (int)fmaf(b0.w, 289.0f, fmaf(b1.w, 17.0f, b2.w));

        atomicAdd(&hist[m0], 1);
        atomicAdd(&hist[m1], 1);
        atomicAdd(&hist[m2], 1);
        atomicAdd(&hist[m3], 1);
        atomicAdd(&hist[NBINS + s0], 1);
        atomicAdd(&hist[NBINS + s1], 1);
        atomicAdd(&hist[NBINS + s2], 1);
        atomicAdd(&hist[NBINS + s3], 1);
    }
    __syncthreads();

    // per-block dot: acc[f] += hist_m[j]*msb_row[j][f] + hist_l[j]*lsb_row[j][f]
    int acc[NFEAT];
#pragma unroll
    for (int f = 0; f < NFEAT; ++f) acc[f] = 0;

    for (int j = threadIdx.x; j < NBINS; j += MT) {
        int hm = hist[j];
        int hl = hist[NBINS + j];
        const int* rm = cm + j * 5;
        const int* rl = cl + j * 5;
#pragma unroll
        for (int k = 0; k < 5; ++k) {
            int wm = rm[k];
            int wl = rl[k];
            acc[4 * k + 0] += hm * ((wm << 24) >> 24) + hl * ((wl << 24) >> 24);
            acc[4 * k + 1] += hm * ((wm << 16) >> 24) + hl * ((wl << 16) >> 24);
            acc[4 * k + 2] += hm * ((wm << 8) >> 24) + hl * ((wl << 8) >> 24);
            acc[4 * k + 3] += hm * (wm >> 24) + hl * (wl >> 24);
        }
    }

    // wave butterfly reduce -> LDS per-wave rows -> threads 0..19 fold 16 rows
    const int lane = threadIdx.x & 63;
    const int wv = threadIdx.x >> 6;
#pragma unroll
    for (int f = 0; f < NFEAT; ++f) {
        int v = acc[f];
#pragma unroll
        for (int o = 32; o > 0; o >>= 1) v += __shfl_xor(v, o, 64);
        if (lane == 0) wsum[wv][f] = v;
    }
    __syncthreads();
    if (threadIdx.x < NFEAT) {
        int f = threadIdx.x;
        int s = 0;
#pragma unroll
        for (int w = 0; w < MT / 64; ++w) s += wsum[w][f];
        partial[blockIdx.x * NFEAT + f] = s;
    }
    // release: each writer fences its own store, then block signals completion
    __threadfence();
    __syncthreads();
    if (threadIdx.x == 0) is_last = (atomicAdd(done, 1u) == (unsigned)(MB - 1));
    __syncthreads();

    if (is_last) {
        __threadfence();  // acquire
        // reduce 512 x 20 partials via LDS atomics (reuse hist[0..19])
        if (threadIdx.x < NFEAT) hist[threadIdx.x] = 0;
        __syncthreads();
        for (int i = threadIdx.x; i < MB * NFEAT; i += MT)
            atomicAdd(&hist[i % NFEAT], partial[i]);
        __syncthreads();
        if (threadIdx.x < NFEAT) {
            // mean*4 = S / 2^20 exact in double; RNE rint == jnp.round
            double m4 = (double)hist[threadIdx.x] * (1.0 / 1048576.0);
            float v = (float)(rint(m4) * 0.25);
            v = fminf(fmaxf(v, -32.0f), 31.75f);
            out[threadIdx.x] = v;
        }
    }
}

extern "C" void kernel_launch(void* const* d_in, const int* in_sizes, int n_in,
                              void* d_out, int out_size, void* d_ws, size_t ws_size,
                              hipStream_t stream) {
    const float* xin = (const float*)d_in[0];
    const float* xs = (const float*)d_in[1];
    const int* msb = (const int*)d_in[2];
    const int* lsb = (const int*)d_in[3];
    float* out = (float*)d_out;

    // workspace: cm (96 KiB) | cl (96 KiB) | partial (512*20*4 = 40 KiB) | done
    int* cm = (int*)d_ws;
    int* cl = (int*)((char*)d_ws + 98304);
    int* partial = (int*)((char*)d_ws + 2 * 98304);
    unsigned* done = (unsigned*)((char*)d_ws + 2 * 98304 + 40960);

    compact_k<<<96, 256, 0, stream>>>(msb, lsb, cm, cl, done);
    feat_main<<<MB, MT, 0, stream>>>(xin, xs, cm, cl, partial, done, out);
}

// Round 4
// 249.742 us; speedup vs baseline: 1.0370x; 1.0370x over previous
//
#include <hip/hip_runtime.h>

// FeatLUT: out[f] = quantize( mean_p( msb[idx_m(p)][f] + lsb[idx_l(p)][f] ) )
// idx = 16*(289*c0 + 17*c1 + c2)  -> only 17^3 = 4913 distinct rows used.
// R1: same-cacheline global atomics serialize (417us) -> per-block partials.
// R2: 1024x256, SDWA dot = 54us (VALU 32%, dot-dominated).
// R3: 1024-thread blocks -> VGPR forced to 32 -> spills -> 166us. Reverted.
// R4: u16-packed hist + u8 quad repack + v_dot4_i32_i8 dot (flag-guarded exact
//     fallback), 1280 blocks x 256 (5 blocks/CU, LDS ~29.8KB).

#define NBINS 4913            // 17^3
#define NPIX  (2048 * 2048)
#define G4    (NPIX / 4)      // 1048576 float4 groups per channel plane
#define NFEAT 20
#define WPT   2457            // u32 words per table histogram (u16 pairs, 4914 slots)
#define HWORDS (2 * WPT)      // 4914 words total (msb @0, lsb @WPT)
#define QPT   1229            // quads (4 bins) per table
#define MB2   1280            // main grid: 5 blocks/CU
#define MT2   256

#if defined(__has_builtin)
#if __has_builtin(__builtin_amdgcn_sdot4)
#define HAS_SDOT4 1
#endif
#endif

static __device__ __forceinline__ int dot4i8(int a, int b, int c) {
#ifdef HAS_SDOT4
    return __builtin_amdgcn_sdot4(a, b, c, false);
#else
    c += ((a << 24) >> 24) * ((b << 24) >> 24);
    c += ((a << 16) >> 24) * ((b << 16) >> 24);
    c += ((a << 8) >> 24) * ((b << 8) >> 24);
    c += (a >> 24) * (b >> 24);
    return c;
#endif
}

// ---------------------------------------------------------------------------
// Kernel 0: compact used LUT rows (row 16*b) into f-major quad-packed int8:
// cm4[f*QPT + q] = bytes (t[4q][f], t[4q+1][f], t[4q+2][f], t[4q+3][f]).
// Handles both harness table layouts (raw int8 bytes, or int8 widened to
// int32 — random packed bytes never look like 16 ints in [-32,32)).
// Also zeroes the completion counter.
// ---------------------------------------------------------------------------
__global__ __launch_bounds__(256) void compact_k(const int* __restrict__ msb,
                                                 const int* __restrict__ lsb,
                                                 int* __restrict__ cm4,
                                                 int* __restrict__ cl4,
                                                 unsigned* __restrict__ done) {
    if (blockIdx.x == 0 && threadIdx.x == 0) *done = 0u;

    int ok = 1;
#pragma unroll
    for (int i = 0; i < 16; ++i) {
        int v = msb[i];
        ok &= (v >= -32 && v < 32);
    }
    const bool is_int32 = (ok != 0);

    const int total = NFEAT * QPT;
    const int stride = gridDim.x * 256;
    for (int o = blockIdx.x * 256 + threadIdx.x; o < total; o += stride) {
        int f = o / QPT;
        int q = o - f * QPT;
        unsigned pm = 0, pl = 0;
#pragma unroll
        for (int i = 0; i < 4; ++i) {
            int b = 4 * q + i;
            unsigned bm = 0, bl = 0;
            if (b < NBINS) {
                if (is_int32) {
                    bm = (unsigned)msb[320 * b + f] & 0xFFu;   // row 16b -> elem 320b
                    bl = (unsigned)lsb[320 * b + f] & 0xFFu;
                } else {
                    int ba = 320 * b + f;                       // byte address
                    bm = ((const unsigned char*)msb)[ba];
                    bl = ((const unsigned char*)lsb)[ba];
                }
            }
            pm |= bm << (8 * i);
            pl |= bl << (8 * i);
        }
        cm4[o] = (int)pm;
        cl4[o] = (int)pl;
    }
}

// ---------------------------------------------------------------------------
// Kernel 1: main. MB2 x MT2 (4 waves/block, 5 blocks/CU).
//  - u16-packed LDS histograms (4914 u32 words)
//  - float4 streaming (grid-stride, ~3-4 iters)
//  - repack counts to u8 quads (flag if any count >= 128 -> exact fallback)
//  - sdot4 dot vs f-major quad tables, wave reduce, per-block partial
//  - last block reduces MB2 partials and writes d_out
// ---------------------------------------------------------------------------
__global__ __launch_bounds__(MT2) void feat_main(const float* __restrict__ xin,
                                                 const float* __restrict__ xs,
                                                 const int* __restrict__ cm4,
                                                 const int* __restrict__ cl4,
                                                 int* __restrict__ partial,
                                                 unsigned* __restrict__ done,
                                                 float* __restrict__ out) {
    __shared__ unsigned h32[HWORDS];   // u16-pair histograms: msb @0, lsb @WPT
    __shared__ int lo[2 * QPT];        // u8-quad repack: msb @0, lsb @QPT
    __shared__ int wsum[MT2 / 64][NFEAT];
    __shared__ int flag;
    __shared__ unsigned is_last;

    for (int i = threadIdx.x; i < HWORDS; i += MT2) h32[i] = 0u;
    if (threadIdx.x == 0) flag = 0;
    __syncthreads();

    // ---- stream + histogram ----
    const float4* a = (const float4*)xin;
    const float4* b = (const float4*)xs;
    for (int g = blockIdx.x * MT2 + threadIdx.x; g < G4; g += MB2 * MT2) {
        float4 a0 = a[g], a1 = a[g + G4], a2 = a[g + 2 * G4];
        float4 b0 = b[g], b1 = b[g + G4], b2 = b[g + 2 * G4];

        int m0 = (int)fmaf(a0.x, 289.0f, fmaf(a1.x, 17.0f, a2.x));
        int m1 = (int)fmaf(a0.y, 289.0f, fmaf(a1.y, 17.0f, a2.y));
        int m2 = (int)fmaf(a0.z, 289.0f, fmaf(a1.z, 17.0f, a2.z));
        int m3 = (int)fmaf(a0.w, 289.0f, fmaf(a1.w, 17.0f, a2.w));
        int s0 = (int)fmaf(b0.x, 289.0f, fmaf(b1.x, 17.0f, b2.x));
        int s1 = (int)fmaf(b0.y, 289.0f, fmaf(b1.y, 17.0f, b2.y));
        int s2 = (int)fmaf(b0.z, 289.0f, fmaf(b1.z, 17.0f, b2.z));
        int s3 = (int)fmaf(b0.w, 289.0f, fmaf(b1.w, 17.0f, b2.w));

        atomicAdd(&h32[m0 >> 1], 1u << ((m0 & 1) << 4));
        atomicAdd(&h32[m1 >> 1], 1u << ((m1 & 1) << 4));
        atomicAdd(&h32[m2 >> 1], 1u << ((m2 & 1) << 4));
        atomicAdd(&h32[m3 >> 1], 1u << ((m3 & 1) << 4));
        atomicAdd(&h32[WPT + (s0 >> 1)], 1u << ((s0 & 1) << 4));
        atomicAdd(&h32[WPT + (s1 >> 1)], 1u << ((s1 & 1) << 4));
        atomicAdd(&h32[WPT + (s2 >> 1)], 1u << ((s2 & 1) << 4));
        atomicAdd(&h32[WPT + (s3 >> 1)], 1u << ((s3 & 1) << 4));
    }
    __syncthreads();

    // ---- repack u16 counts -> u8 quads; flag any count >= 128 ----
    int bad = 0;
    for (int i = threadIdx.x; i < 2 * QPT; i += MT2) {
        int tb = (i >= QPT);
        int q = i - tb * QPT;
        int base = tb * WPT;
        unsigned w0 = h32[base + 2 * q];
        unsigned w1 = (2 * q + 1 < WPT) ? h32[base + 2 * q + 1] : 0u;
        bad |= (int)((w0 | w1) & 0xFF80FF80u);
        lo[i] = (int)((w0 & 0xFFu) | ((w0 >> 16) << 8 & 0xFF00u) |
                      ((w1 & 0xFFu) << 16) | ((w1 >> 16) << 24));
    }
    if (bad) flag = 1;
    __syncthreads();

    // ---- per-block dot ----
    int acc[NFEAT];
#pragma unroll
    for (int f = 0; f < NFEAT; ++f) acc[f] = 0;

    if (flag == 0) {
        // fast path: 1 sdot4 per 4 bins per feature per table
        for (int q = threadIdx.x; q < QPT; q += MT2) {
            int lom = lo[q];
            int lol = lo[QPT + q];
#pragma unroll
            for (int f = 0; f < NFEAT; ++f) {
                acc[f] = dot4i8(lom, cm4[f * QPT + q], acc[f]);
                acc[f] = dot4i8(lol, cl4[f * QPT + q], acc[f]);
            }
        }
    } else {
        // exact fallback (some per-block count >= 128; practically never)
        for (int j = threadIdx.x; j < NBINS; j += MT2) {
            int hm = (int)((h32[j >> 1] >> ((j & 1) << 4)) & 0xFFFFu);
            int hl = (int)((h32[WPT + (j >> 1)] >> ((j & 1) << 4)) & 0xFFFFu);
            int q = j >> 2, sh = 24 - ((j & 3) << 3);
#pragma unroll
            for (int f = 0; f < NFEAT; ++f) {
                int tm = ((int)((unsigned)cm4[f * QPT + q] << sh)) >> 24;
                int tl = ((int)((unsigned)cl4[f * QPT + q] << sh)) >> 24;
                acc[f] += hm * tm + hl * tl;
            }
        }
    }

    // ---- reduce: wave butterfly -> LDS rows -> per-block partial ----
    const int lane = threadIdx.x & 63;
    const int wv = threadIdx.x >> 6;
#pragma unroll
    for (int f = 0; f < NFEAT; ++f) {
        int v = acc[f];
#pragma unroll
        for (int o = 32; o > 0; o >>= 1) v += __shfl_xor(v, o, 64);
        if (lane == 0) wsum[wv][f] = v;
    }
    __syncthreads();
    if (threadIdx.x < NFEAT) {
        int f = threadIdx.x;
        int s = 0;
#pragma unroll
        for (int w = 0; w < MT2 / 64; ++w) s += wsum[w][f];
        partial[blockIdx.x * NFEAT + f] = s;
    }
    __threadfence();
    __syncthreads();
    if (threadIdx.x == 0) is_last = (atomicAdd(done, 1u) == (unsigned)(MB2 - 1));
    __syncthreads();

    if (is_last) {
        __threadfence();  // acquire
        if (threadIdx.x < NFEAT) h32[threadIdx.x] = 0u;
        __syncthreads();
        for (int i = threadIdx.x; i < MB2 * NFEAT; i += MT2)
            atomicAdd((int*)&h32[i % NFEAT], partial[i]);
        __syncthreads();
        if (threadIdx.x < NFEAT) {
            // mean*4 = S / 2^20 exact in double; RNE rint == jnp.round
            double m4 = (double)(int)h32[threadIdx.x] * (1.0 / 1048576.0);
            float v = (float)(rint(m4) * 0.25);
            v = fminf(fmaxf(v, -32.0f), 31.75f);
            out[threadIdx.x] = v;
        }
    }
}

extern "C" void kernel_launch(void* const* d_in, const int* in_sizes, int n_in,
                              void* d_out, int out_size, void* d_ws, size_t ws_size,
                              hipStream_t stream) {
    const float* xin = (const float*)d_in[0];
    const float* xs = (const float*)d_in[1];
    const int* msb = (const int*)d_in[2];
    const int* lsb = (const int*)d_in[3];
    float* out = (float*)d_out;

    // ws: cm4 (96.2KB pad 98560) | cl4 | partial (1280*20*4=102400) | done
    int* cm4 = (int*)d_ws;
    int* cl4 = (int*)((char*)d_ws + 98560);
    int* partial = (int*)((char*)d_ws + 2 * 98560);
    unsigned* done = (unsigned*)((char*)d_ws + 2 * 98560 + 102400);

    compact_k<<<96, 256, 0, stream>>>(msb, lsb, cm4, cl4, done);
    feat_main<<<MB2, MT2, 0, stream>>>(xin, xs, cm4, cl4, partial, done, out);
}

// Round 5
// 181.196 us; speedup vs baseline: 1.4293x; 1.3783x over previous
//
#include <hip/hip_runtime.h>

// FeatLUT: out[f] = quantize( mean_p( msb[idx_m(p)][f] + lsb[idx_l(p)][f] ) )
// idx = 16*(289*c0 + 17*c1 + c2) -> only 17^3 = 4913 distinct rows used.
// R1: same-cacheline global atomics serialize (417us) -> per-block partials.
// R2: 1024x256 stream+LDS-hist+per-block dot = 54us (VALU 32%, dot ~2/3 of it).
// R3: 1024-thread blocks -> VGPR 32 -> spills -> 166us (VALU 6%).
// R4: sdot4 dot with 40-load unrolled f-loop -> VGPR 64 cap -> spills -> 152us
//     (VALU 6.7%, HBM-insensitive). The per-block dot is a register cliff.
// R5: remove the per-block dot entirely. Stage 1 streams + histograms and
//     writes provably-safe u16 per-block histograms (20.2MB, coalesced, no
//     atomics). Stage 2 column-sums histograms and dots ONCE. Fallback to the
//     proven R2 kernel if ws_size can't hold the histograms.

#define NBINS 4913            // 17^3
#define NPIX  (2048 * 2048)
#define G4    (NPIX / 4)      // 1048576 float4 groups per channel plane
#define NFEAT 20
#define WPH   2457            // u32 words per table histogram (u16 pairs, 4914 slots)
#define HROW  (2 * WPH)       // 4914 valid words per block row (msb | lsb)
#define ROWW  4928            // padded row stride in words (multiple of 64)
#define SB    1024            // stage-1 blocks (4 exact stream iters)
#define STRIPS 77             // ceil(HROW/64)
#define RGRP  4               // row groups per strip in stage 2
#define G2    (STRIPS * RGRP) // 308 stage-2 blocks
#define RPG   (SB / RGRP)     // 256 rows per group

// ---------------------------------------------------------------------------
// Kernel 0: compact used LUT rows (row 16*j) into dense 20B rows (5 dwords),
// row-major (cm[j*5+k]). Handles both harness table layouts (raw int8 bytes,
// or int8 widened to int32 — random packed bytes never look like 16
// consecutive ints in [-32,32)). Also zeroes the completion counter.
// ---------------------------------------------------------------------------
__global__ __launch_bounds__(256) void compact_k(const int* __restrict__ msb,
                                                 const int* __restrict__ lsb,
                                                 int* __restrict__ cm,
                                                 int* __restrict__ cl,
                                                 unsigned* __restrict__ done) {
    if (blockIdx.x == 0 && threadIdx.x == 0) *done = 0u;

    int ok = 1;
#pragma unroll
    for (int i = 0; i < 16; ++i) {
        int v = msb[i];
        ok &= (v >= -32 && v < 32);
    }
    const bool is_int32 = (ok != 0);

    const int total = NBINS * 5;
    const int stride = gridDim.x * 256;
    for (int t = blockIdx.x * 256 + threadIdx.x; t < total; t += stride) {
        int j = t / 5;
        int k = t - j * 5;
        int wm, wl;
        if (is_int32) {
            const int* rm = msb + j * 320 + k * 4;  // row 16j -> elem 320j
            const int* rl = lsb + j * 320 + k * 4;
            wm = (int)((unsigned)(rm[0] & 0xff) | ((unsigned)(rm[1] & 0xff) << 8) |
                       ((unsigned)(rm[2] & 0xff) << 16) | ((unsigned)(rm[3] & 0xff) << 24));
            wl = (int)((unsigned)(rl[0] & 0xff) | ((unsigned)(rl[1] & 0xff) << 8) |
                       ((unsigned)(rl[2] & 0xff) << 16) | ((unsigned)(rl[3] & 0xff) << 24));
        } else {
            wm = msb[j * 80 + k];  // row 16j at byte 320j -> dword 80j
            wl = lsb[j * 80 + k];
        }
        cm[t] = wm;
        cl[t] = wl;
    }
}

// ---------------------------------------------------------------------------
// Stage 1: stream + LDS histogram, then write packed u16 per-block histogram.
// Per-block per-table pixel count = 4096 -> every count provably fits u16.
// No dot -> low register pressure (R3/R4 lesson).
// ---------------------------------------------------------------------------
__global__ __launch_bounds__(256) void hist_k(const float* __restrict__ xin,
                                              const float* __restrict__ xs,
                                              unsigned* __restrict__ ghist) {
    __shared__ int hist[2 * NBINS];  // [0,NBINS): msb, [NBINS,2*NBINS): lsb
    for (int i = threadIdx.x; i < 2 * NBINS; i += 256) hist[i] = 0;
    __syncthreads();

    const float4* a = (const float4*)xin;
    const float4* b = (const float4*)xs;
    for (int g = blockIdx.x * 256 + threadIdx.x; g < G4; g += SB * 256) {
        float4 a0 = a[g], a1 = a[g + G4], a2 = a[g + 2 * G4];
        float4 b0 = b[g], b1 = b[g + G4], b2 = b[g + 2 * G4];

        int m0 = (int)fmaf(a0.x, 289.0f, fmaf(a1.x, 17.0f, a2.x));
        int m1 = (int)fmaf(a0.y, 289.0f, fmaf(a1.y, 17.0f, a2.y));
        int m2 = (int)fmaf(a0.z, 289.0f, fmaf(a1.z, 17.0f, a2.z));
        int m3 = (int)fmaf(a0.w, 289.0f, fmaf(a1.w, 17.0f, a2.w));
        int s0 = (int)fmaf(b0.x, 289.0f, fmaf(b1.x, 17.0f, b2.x));
        int s1 = (int)fmaf(b0.y, 289.0f, fmaf(b1.y, 17.0f, b2.y));
        int s2 = (int)fmaf(b0.z, 289.0f, fmaf(b1.z, 17.0f, b2.z));
        int s3 = (int)fmaf(b0.w, 289.0f, fmaf(b1.w, 17.0f, b2.w));

        atomicAdd(&hist[m0], 1);
        atomicAdd(&hist[m1], 1);
        atomicAdd(&hist[m2], 1);
        atomicAdd(&hist[m3], 1);
        atomicAdd(&hist[NBINS + s0], 1);
        atomicAdd(&hist[NBINS + s1], 1);
        atomicAdd(&hist[NBINS + s2], 1);
        atomicAdd(&hist[NBINS + s3], 1);
    }
    __syncthreads();

    // pack pairs of u16 counts into u32 words, coalesced row write
    unsigned* row = ghist + (size_t)blockIdx.x * ROWW;
    for (int w = threadIdx.x; w < HROW; w += 256) {
        int tb = (w >= WPH);
        int wi = w - tb * WPH;
        int j0 = tb * NBINS + 2 * wi;
        unsigned lo = (unsigned)hist[j0];
        unsigned hi = (2 * wi + 1 < NBINS) ? (unsigned)hist[j0 + 1] : 0u;
        row[w] = lo | (hi << 16);
    }
}

// ---------------------------------------------------------------------------
// Stage 2: block (strip, grp) sums a 64-word column strip over 256 rows
// (coalesced 256B wave reads), dots the ~128 summed bins against the compact
// table, block-reduces acc[20] -> per-block partial; last block finalizes.
// ---------------------------------------------------------------------------
__global__ __launch_bounds__(256) void reduce_k(const unsigned* __restrict__ ghist,
                                                const int* __restrict__ cm,
                                                const int* __restrict__ cl,
                                                int* __restrict__ partial,
                                                unsigned* __restrict__ done,
                                                float* __restrict__ out) {
    __shared__ int scnt[128];
    __shared__ int wsum[4][NFEAT];
    __shared__ unsigned is_last;

    const int strip = blockIdx.x % STRIPS;
    const int grp = blockIdx.x / STRIPS;
    const int w0 = strip * 64;
    const int wlane = threadIdx.x & 63;
    const int wv = threadIdx.x >> 6;

    if (threadIdx.x < 128) scnt[threadIdx.x] = 0;
    __syncthreads();

    // column sums over this row group (lanes read 64 consecutive words)
    unsigned slo = 0, shi = 0;
    const int w = w0 + wlane;
    if (w < HROW) {
        const int b0 = grp * RPG;
        for (int b = b0 + wv; b < b0 + RPG; b += 4) {
            unsigned v = ghist[(size_t)b * ROWW + w];
            slo += v & 0xFFFFu;
            shi += v >> 16;
        }
    }
    atomicAdd(&scnt[2 * wlane], (int)slo);
    atomicAdd(&scnt[2 * wlane + 1], (int)shi);
    __syncthreads();

    // dot the strip's bins against table rows
    int acc[NFEAT];
#pragma unroll
    for (int f = 0; f < NFEAT; ++f) acc[f] = 0;

    if (threadIdx.x < 128) {
        int s = threadIdx.x;
        int word = w0 + (s >> 1);
        if (word < HROW) {
            int tb = (word >= WPH);
            int wi = word - tb * WPH;
            int j = 2 * wi + (s & 1);
            if (j < NBINS) {
                int c = scnt[s];
                if (c) {
                    const int* r = (tb ? cl : cm) + j * 5;
#pragma unroll
                    for (int k = 0; k < 5; ++k) {
                        int t = r[k];
                        acc[4 * k + 0] += c * ((t << 24) >> 24);
                        acc[4 * k + 1] += c * ((t << 16) >> 24);
                        acc[4 * k + 2] += c * ((t << 8) >> 24);
                        acc[4 * k + 3] += c * (t >> 24);
                    }
                }
            }
        }
    }

    // block reduce: wave butterfly -> LDS rows -> per-block partial
    const int lane = threadIdx.x & 63;
#pragma unroll
    for (int f = 0; f < NFEAT; ++f) {
        int v = acc[f];
#pragma unroll
        for (int o = 32; o > 0; o >>= 1) v += __shfl_xor(v, o, 64);
        if (lane == 0) wsum[wv][f] = v;
    }
    __syncthreads();
    if (threadIdx.x < NFEAT) {
        int f = threadIdx.x;
        partial[blockIdx.x * NFEAT + f] = wsum[0][f] + wsum[1][f] + wsum[2][f] + wsum[3][f];
    }
    __threadfence();
    __syncthreads();
    if (threadIdx.x == 0) is_last = (atomicAdd(done, 1u) == (unsigned)(G2 - 1));
    __syncthreads();

    if (is_last) {
        __threadfence();  // acquire
        if (threadIdx.x < NFEAT) scnt[threadIdx.x] = 0;
        __syncthreads();
        for (int i = threadIdx.x; i < G2 * NFEAT; i += 256)
            atomicAdd(&scnt[i % NFEAT], partial[i]);
        __syncthreads();
        if (threadIdx.x < NFEAT) {
            // mean*4 = S / 2^20 exact in double; RNE rint == jnp.round
            double m4 = (double)scnt[threadIdx.x] * (1.0 / 1048576.0);
            float v = (float)(rint(m4) * 0.25);
            v = fminf(fmaxf(v, -32.0f), 31.75f);
            out[threadIdx.x] = v;
        }
    }
}

// ---------------------------------------------------------------------------
// Fallback (R2 verbatim, proven 54us): stream + hist + per-block dot, used
// only if ws_size can't hold the stage-1 histograms.
// ---------------------------------------------------------------------------
__global__ __launch_bounds__(256) void feat_fallback(const float* __restrict__ xin,
                                                     const float* __restrict__ xs,
                                                     const int* __restrict__ cm,
                                                     const int* __restrict__ cl,
                                                     int* __restrict__ partial,
                                                     unsigned* __restrict__ done,
                                                     float* __restrict__ out) {
    __shared__ int hist[2 * NBINS];
    __shared__ int wsum[4][NFEAT];
    __shared__ unsigned is_last;
    for (int i = threadIdx.x; i < 2 * NBINS; i += 256) hist[i] = 0;
    __syncthreads();

    const float4* a = (const float4*)xin;
    const float4* b = (const float4*)xs;
    for (int g = blockIdx.x * 256 + threadIdx.x; g < G4; g += SB * 256) {
        float4 a0 = a[g], a1 = a[g + G4], a2 = a[g + 2 * G4];
        float4 b0 = b[g], b1 = b[g + G4], b2 = b[g + 2 * G4];
        int m0 = (int)fmaf(a0.x, 289.0f, fmaf(a1.x, 17.0f, a2.x));
        int m1 = (int)fmaf(a0.y, 289.0f, fmaf(a1.y, 17.0f, a2.y));
        int m2 = (int)fmaf(a0.z, 289.0f, fmaf(a1.z, 17.0f, a2.z));
        int m3 = (int)fmaf(a0.w, 289.0f, fmaf(a1.w, 17.0f, a2.w));
        int s0 = (int)fmaf(b0.x, 289.0f, fmaf(b1.x, 17.0f, b2.x));
        int s1 = (int)fmaf(b0.y, 289.0f, fmaf(b1.y, 17.0f, b2.y));
        int s2 = (int)fmaf(b0.z, 289.0f, fmaf(b1.z, 17.0f, b2.z));
        int s3 = (int)fmaf(b0.w, 289.0f, fmaf(b1.w, 17.0f, b2.w));
        atomicAdd(&hist[m0], 1);
        atomicAdd(&hist[m1], 1);
        atomicAdd(&hist[m2], 1);
        atomicAdd(&hist[m3], 1);
        atomicAdd(&hist[NBINS + s0], 1);
        atomicAdd(&hist[NBINS + s1], 1);
        atomicAdd(&hist[NBINS + s2], 1);
        atomicAdd(&hist[NBINS + s3], 1);
    }
    __syncthreads();

    int acc[NFEAT];
#pragma unroll
    for (int f = 0; f < NFEAT; ++f) acc[f] = 0;
    for (int j = threadIdx.x; j < NBINS; j += 256) {
        int hm = hist[j];
        int hl = hist[NBINS + j];
        const int* rm = cm + j * 5;
        const int* rl = cl + j * 5;
#pragma unroll
        for (int k = 0; k < 5; ++k) {
            int wm = rm[k];
            int wl = rl[k];
            acc[4 * k + 0] += hm * ((wm << 24) >> 24) + hl * ((wl << 24) >> 24);
            acc[4 * k + 1] += hm * ((wm << 16) >> 24) + hl * ((wl << 16) >> 24);
            acc[4 * k + 2] += hm * ((wm << 8) >> 24) + hl * ((wl << 8) >> 24);
            acc[4 * k + 3] += hm * (wm >> 24) + hl * (wl >> 24);
        }
    }

    const int lane = threadIdx.x & 63;
    const int wv = threadIdx.x >> 6;
#pragma unroll
    for (int f = 0; f < NFEAT; ++f) {
        int v = acc[f];
#pragma unroll
        for (int o = 32; o > 0; o >>= 1) v += __shfl_xor(v, o, 64);
        if (lane == 0) wsum[wv][f] = v;
    }
    __syncthreads();
    if (threadIdx.x < NFEAT) {
        int f = threadIdx.x;
        partial[blockIdx.x * NFEAT + f] = wsum[0][f] + wsum[1][f] + wsum[2][f] + wsum[3][f];
    }
    __threadfence();
    __syncthreads();
    if (threadIdx.x == 0) is_last = (atomicAdd(done, 1u) == (unsigned)(SB - 1));
    __syncthreads();
    if (is_last) {
        __threadfence();
        if (threadIdx.x < NFEAT) hist[threadIdx.x] = 0;
        __syncthreads();
        for (int i = threadIdx.x; i < SB * NFEAT; i += 256)
            atomicAdd(&hist[i % NFEAT], partial[i]);
        __syncthreads();
        if (threadIdx.x < NFEAT) {
            double m4 = (double)hist[threadIdx.x] * (1.0 / 1048576.0);
            float v = (float)(rint(m4) * 0.25);
            v = fminf(fmaxf(v, -32.0f), 31.75f);
            out[threadIdx.x] = v;
        }
    }
}

extern "C" void kernel_launch(void* const* d_in, const int* in_sizes, int n_in,
                              void* d_out, int out_size, void* d_ws, size_t ws_size,
                              hipStream_t stream) {
    const float* xin = (const float*)d_in[0];
    const float* xs = (const float*)d_in[1];
    const int* msb = (const int*)d_in[2];
    const int* lsb = (const int*)d_in[3];
    float* out = (float*)d_out;

    // ws: cm 96KiB | cl 96KiB | partial 80KiB | done | pad | ghist 20.19MB
    char* base = (char*)d_ws;
    int* cm = (int*)base;
    int* cl = (int*)(base + 98304);
    int* partial = (int*)(base + 196608);
    unsigned* done = (unsigned*)(base + 196608 + 81920);
    unsigned* ghist = (unsigned*)(base + 278784);  // 256B-aligned
    const size_t need = 278784 + (size_t)SB * ROWW * 4;  // ~20.46 MB

    compact_k<<<96, 256, 0, stream>>>(msb, lsb, cm, cl, done);
    if (ws_size >= need) {
        hist_k<<<SB, 256, 0, stream>>>(xin, xs, ghist);
        reduce_k<<<G2, 256, 0, stream>>>(ghist, cm, cl, partial, done, out);
    } else {
        feat_fallback<<<SB, 256, 0, stream>>>(xin, xs, cm, cl, partial, done, out);
    }
}